// Round 1
// 442.989 us; speedup vs baseline: 1.1078x; 1.1078x over previous
//
#include <hip/hip_runtime.h>

#define NEG_INF (-__builtin_huge_valf())

// Max-plus 5x5 dilation, fp32, NCHW (16,64,256,256), 'same' pad (2,2) with -inf.
//
// Block (64,4) = 4 waves. Output tile: 256 cols x 16 rows per block.
// LDS stages 20 input rows (tile rows -2..+17) x 264 cols:
//   idx 0..3   = -inf left pad   (image cols -4..-1)
//   idx 4..259 = image cols 0..255
//   idx 260..263 = -inf right pad (image cols 256..259)
// 21.1 KB LDS -> 7 blocks/CU (28 waves/CU). Each thread: 4 cols x 4 rows.
// Compute reads are 3x ds_read_b128 at 16B lane stride -> dense, conflict-free.

#define TILE_ROWS 16
#define IN_ROWS   20
#define LDS_W     264

__global__ __launch_bounds__(256, 7)
void semiconv2d_dilate(const float* __restrict__ in,
                       const float* __restrict__ ker,
                       float* __restrict__ out) {
    const int tx  = threadIdx.x;               // 0..63 (lane); col group of 4
    const int ty  = threadIdx.y;               // 0..3 (wave id); row group of 4
    const int lin = (ty << 6) | tx;
    const int r0  = blockIdx.x * TILE_ROWS;    // first output row of tile
    const long long plane = blockIdx.y;        // b*64 + ch

    const float* __restrict__ pin  = in  + plane * 65536;
    float* __restrict__       pout = out + plane * 65536;

    __shared__ __align__(16) float lds[IN_ROWS * LDS_W];

    // 5x5 kernel: uniform addresses -> scalar loads into SGPRs
    float kk[25];
    #pragma unroll
    for (int t = 0; t < 25; ++t) kk[t] = ker[t];

    // ---- stage: -inf col pads (40 float4 slots) ----
    if (lin < 2 * IN_ROWS) {
        const int row  = lin >> 1;
        const int side = lin & 1;
        float4* p = reinterpret_cast<float4*>(&lds[row * LDS_W + (side ? (LDS_W - 4) : 0)]);
        *p = make_float4(NEG_INF, NEG_INF, NEG_INF, NEG_INF);
    }

    // ---- stage: 20 rows, wave-per-row, dense coalesced 1KB per wave ----
    #pragma unroll
    for (int p = 0; p < 5; ++p) {
        const int row = (p << 2) + ty;         // wave ty stages this LDS row
        const int ir  = r0 - 2 + row;          // image row (may be OOB)
        float4 v;
        if (ir >= 0 && ir < 256) {             // wave-uniform branch
            v = *reinterpret_cast<const float4*>(pin + (ir << 8) + (tx << 2));
        } else {
            v = make_float4(NEG_INF, NEG_INF, NEG_INF, NEG_INF);
        }
        *reinterpret_cast<float4*>(&lds[row * LDS_W + 4 + (tx << 2)]) = v;
    }
    __syncthreads();

    // ---- compute: 4 rows x 4 cols per thread ----
    float acc[4][4];
    #pragma unroll
    for (int i = 0; i < 4; ++i)
        #pragma unroll
        for (int x = 0; x < 4; ++x) acc[i][x] = NEG_INF;

    const int c0 = tx << 2;                    // base output col
    // Thread's input rows: LDS rows 4*ty .. 4*ty+7.
    #pragma unroll
    for (int ro = 0; ro < 8; ++ro) {
        const float* lp = &lds[((ty << 2) + ro) * LDS_W + c0];  // LDS idx c0 = image col c0-4
        const float4 A = *reinterpret_cast<const float4*>(lp);
        const float4 B = *reinterpret_cast<const float4*>(lp + 4);
        const float4 C = *reinterpret_cast<const float4*>(lp + 8);
        const float w[12] = {A.x, A.y, A.z, A.w,
                             B.x, B.y, B.z, B.w,
                             C.x, C.y, C.z, C.w};
        // Input row contributes tap u = ro - i to output row i.
        #pragma unroll
        for (int i = 0; i < 4; ++i) {
            const int u = ro - i;
            if (u >= 0 && u < 5) {             // folds at compile time
                #pragma unroll
                for (int v = 0; v < 5; ++v) {
                    const float kv = kk[u * 5 + v];
                    #pragma unroll
                    for (int x = 0; x < 4; ++x)
                        acc[i][x] = fmaxf(acc[i][x], w[x + v + 2] + kv);
                }
            }
        }
    }

    // ---- store: per wave = one row, dense 1KB coalesced ----
    #pragma unroll
    for (int i = 0; i < 4; ++i) {
        float* op = pout + ((r0 + (ty << 2) + i) << 8) + c0;
        *reinterpret_cast<float4*>(op) = make_float4(acc[i][0], acc[i][1], acc[i][2], acc[i][3]);
    }
}

extern "C" void kernel_launch(void* const* d_in, const int* in_sizes, int n_in,
                              void* d_out, int out_size, void* d_ws, size_t ws_size,
                              hipStream_t stream) {
    const float* in  = (const float*)d_in[0];   // (16,64,256,256) fp32
    const float* ker = (const float*)d_in[1];   // (5,5) fp32
    float* out = (float*)d_out;

    dim3 grid(256 / TILE_ROWS, 16 * 64);        // (16, 1024)
    dim3 block(64, 4);
    semiconv2d_dilate<<<grid, block, 0, stream>>>(in, ker, out);
}

// Round 2
// 441.639 us; speedup vs baseline: 1.1112x; 1.0031x over previous
//
#include <hip/hip_runtime.h>

#define NEG_INF (-__builtin_huge_valf())

// Max-plus 5x5 dilation, fp32, NCHW (16,64,256,256), 'same' pad (2,2) with -inf.
//
// Block (64,4) = 4 waves. Each block processes TPB=4 consecutive 16-row tiles
// of one plane (64 output rows), double-buffered through LDS:
//   stage(t+1) via global_load_lds (async, width 16) -> counted vmcnt wait for
//   tile t -> raw s_barrier -> compute tile t (ds_read_b128 + VALU w/ v_max3)
//   -> barrier -> next.
// vmcnt immediates are exact because every wave issues exactly 5 loads per
// stage (OOB halo rows load a clamped row, then are overwritten with -inf
// after the wait, before the barrier).
//
// LDS: 2 x 20 rows x 264 floats = 42.2 KB -> 3 blocks/CU. Latency hiding comes
// from the in-block pipeline (loads for tile t+1 in flight across the compute
// of tile t), not TLP.

#define TILE_ROWS 16
#define IN_ROWS   20        // TILE_ROWS + 4 halo rows
#define LDS_W     264       // 4 -inf pad | 256 data | 4 -inf pad
#define TPB       4         // tiles per block

typedef const __attribute__((address_space(1))) unsigned int GU;
typedef __attribute__((address_space(3))) unsigned int LU;

#define WAIT_VMCNT(N) do { asm volatile("s_waitcnt vmcnt(" #N ")" ::: "memory"); \
                           __builtin_amdgcn_sched_barrier(0); } while (0)
#define WAIT_LGKM0()  do { asm volatile("s_waitcnt lgkmcnt(0)" ::: "memory"); \
                           __builtin_amdgcn_sched_barrier(0); } while (0)
#define BARRIER()     do { __builtin_amdgcn_sched_barrier(0); \
                           __builtin_amdgcn_s_barrier(); \
                           __builtin_amdgcn_sched_barrier(0); } while (0)

__global__ __launch_bounds__(256)
void semiconv2d_dilate(const float* __restrict__ in,
                       const float* __restrict__ ker,
                       float* __restrict__ out) {
    const int tx  = threadIdx.x;               // 0..63 (lane)
    const int ty  = threadIdx.y;               // 0..3 (wave id)
    const int lin = (ty << 6) | tx;
    const long long plane = blockIdx.y;        // b*64 + ch
    const int tile0 = blockIdx.x * TPB;        // first 16-row tile index

    const float* __restrict__ pin  = in  + plane * 65536;
    float* __restrict__       pout = out + plane * 65536;

    __shared__ __align__(16) float lds[2][IN_ROWS * LDS_W];

    // 5x5 kernel: uniform address -> scalar loads (SGPRs)
    float kk[25];
    #pragma unroll
    for (int t = 0; t < 25; ++t) kk[t] = ker[t];

    // -inf column pads for both buffers (constant across tiles; written once)
    if (lin < 2 * IN_ROWS) {
        const int row  = lin >> 1;
        const int side = lin & 1;
        const int off  = row * LDS_W + (side ? (LDS_W - 4) : 0);
        const float4 ni = make_float4(NEG_INF, NEG_INF, NEG_INF, NEG_INF);
        *reinterpret_cast<float4*>(&lds[0][off]) = ni;
        *reinterpret_cast<float4*>(&lds[1][off]) = ni;
    }

    // ---- stage tile t into buffer s: exactly 5 global_load_lds per wave ----
    auto STAGE = [&](int t, int s) {
        const int r0 = (tile0 + t) * TILE_ROWS;
        #pragma unroll
        for (int p = 0; p < 5; ++p) {
            const int row = (p << 2) + ty;     // wave-uniform LDS row
            int ir = r0 - 2 + row;
            ir = ir < 0 ? 0 : (ir > 255 ? 255 : ir);   // clamp: keeps vm counts uniform
            const float* gp = pin + (ir << 8) + (tx << 2);
            float* lp = &lds[s][row * LDS_W + 4];       // wave-uniform base, lane*16B dest
            __builtin_amdgcn_global_load_lds((GU*)gp, (LU*)lp, 16, 0, 0);
        }
    };

    // ---- overwrite OOB halo rows with -inf (call after the counted wait) ----
    auto FIXOOB = [&](int t, int s) {
        const int r0 = (tile0 + t) * TILE_ROWS;
        if (r0 == 0 || r0 == 240) {            // only edge tiles have OOB rows
            #pragma unroll
            for (int p = 0; p < 5; ++p) {
                const int row = (p << 2) + ty;
                const int ir = r0 - 2 + row;
                if (ir < 0 || ir > 255) {      // wave-uniform branch
                    *reinterpret_cast<float4*>(&lds[s][row * LDS_W + 4 + (tx << 2)]) =
                        make_float4(NEG_INF, NEG_INF, NEG_INF, NEG_INF);
                }
            }
        }
    };

    // ---- compute tile t from buffer s; includes the 4 stores ----
    auto COMPUTE = [&](int t, int s) {
        const int r0 = (tile0 + t) * TILE_ROWS;
        const int c0 = tx << 2;                // base output col
        float acc[4][4];
        #pragma unroll
        for (int i = 0; i < 4; ++i)
            #pragma unroll
            for (int x = 0; x < 4; ++x) acc[i][x] = NEG_INF;

        #pragma unroll
        for (int ro = 0; ro < 8; ++ro) {
            const float* lp = &lds[s][((ty << 2) + ro) * LDS_W + c0];
            const float4 A = *reinterpret_cast<const float4*>(lp);
            const float4 B = *reinterpret_cast<const float4*>(lp + 4);
            const float4 C = *reinterpret_cast<const float4*>(lp + 8);
            const float w[12] = {A.x, A.y, A.z, A.w,
                                 B.x, B.y, B.z, B.w,
                                 C.x, C.y, C.z, C.w};
            #pragma unroll
            for (int i = 0; i < 4; ++i) {
                const int u = ro - i;
                if (u >= 0 && u < 5) {         // folds at compile time
                    #pragma unroll
                    for (int x = 0; x < 4; ++x) {
                        const float t0 = w[x + 2] + kk[u * 5 + 0];
                        const float t1 = w[x + 3] + kk[u * 5 + 1];
                        const float t2 = w[x + 4] + kk[u * 5 + 2];
                        const float t3 = w[x + 5] + kk[u * 5 + 3];
                        const float t4 = w[x + 6] + kk[u * 5 + 4];
                        const float m1 = fmaxf(fmaxf(t0, t1), t2);              // v_max3
                        const float m2 = fmaxf(fmaxf(t3, t4), acc[i][x]);       // v_max3
                        acc[i][x] = fmaxf(m1, m2);
                    }
                }
            }
        }

        #pragma unroll
        for (int i = 0; i < 4; ++i) {
            float* op = pout + ((r0 + (ty << 2) + i) << 8) + c0;
            *reinterpret_cast<float4*>(op) =
                make_float4(acc[i][0], acc[i][1], acc[i][2], acc[i][3]);
        }
    };

    // ---- pipelined main sequence (per-wave VMEM stream annotated) ----
    STAGE(0, 0);                 // L0 = 5 loads
    STAGE(1, 1);                 // L1 = 5 loads
    WAIT_VMCNT(5);               // L0 done (newer in flight: L1=5)
    FIXOOB(0, 0);
    WAIT_LGKM0();                // pads + oob writes visible
    BARRIER();
    COMPUTE(0, 0);               // S0 = 4 stores
    BARRIER();                   // all waves done reading buf0

    STAGE(2, 0);                 // L2
    WAIT_VMCNT(9);               // L1 done (newer: S0=4 + L2=5)
    FIXOOB(1, 1);
    WAIT_LGKM0();
    BARRIER();
    COMPUTE(1, 1);               // S1
    BARRIER();

    STAGE(3, 1);                 // L3
    WAIT_VMCNT(9);               // L2 done (newer: S1=4 + L3=5)
    FIXOOB(2, 0);
    WAIT_LGKM0();
    BARRIER();
    COMPUTE(2, 0);               // S2
    BARRIER();

    WAIT_VMCNT(4);               // L3 done (newer: S2=4)
    FIXOOB(3, 1);
    WAIT_LGKM0();
    BARRIER();
    COMPUTE(3, 1);
}

extern "C" void kernel_launch(void* const* d_in, const int* in_sizes, int n_in,
                              void* d_out, int out_size, void* d_ws, size_t ws_size,
                              hipStream_t stream) {
    const float* in  = (const float*)d_in[0];   // (16,64,256,256) fp32
    const float* ker = (const float*)d_in[1];   // (5,5) fp32
    float* out = (float*)d_out;

    // 1024 planes; each block covers 64 output rows (4 tiles of 16).
    dim3 grid(256 / (TILE_ROWS * TPB), 16 * 64);   // (4, 1024)
    dim3 block(64, 4);
    semiconv2d_dilate<<<grid, block, 0, stream>>>(in, ker, out);
}